// Round 1
// baseline (173.347 us; speedup 1.0000x reference)
//
#include <hip/hip_runtime.h>

// QRTDampedResidualHierarchy: the jax.lax.scan collapses analytically.
//   residuals[0]   = tokens            (delta = vec - 0, scaled by DECAY^0 = 1.0 exactly)
//   residuals[1:]  = 0.0 exactly       (delta = vec - vec = +0; _qrt_damp result is discarded)
// So the whole op is: copy 8 MiB, zero-fill the remaining 1 GiB - 8 MiB.
// Pure HBM-write-bound: ~1.082 GB traffic/call -> ~172 us floor at 6.3 TB/s.

extern "C" void kernel_launch(void* const* d_in, const int* in_sizes, int n_in,
                              void* d_out, int out_size, void* d_ws, size_t ws_size,
                              hipStream_t stream) {
    const float* tokens = (const float*)d_in[0];
    float* out = (float*)d_out;

    const size_t lvl0_elems = (size_t)in_sizes[0];          // 256 * 8192 = 2,097,152
    const size_t total_elems = (size_t)out_size;            // 128 * 256 * 8192

    // Level 0: residuals[0] = tokens (bitwise copy).
    hipMemcpyAsync(out, tokens, lvl0_elems * sizeof(float),
                   hipMemcpyDeviceToDevice, stream);

    // Levels 1..127: exactly zero.
    hipMemsetAsync(out + lvl0_elems, 0,
                   (total_elems - lvl0_elems) * sizeof(float), stream);
}